// Round 1
// baseline (45.972 us; speedup 1.0000x reference)
//
#include <hip/hip_runtime.h>
#include <math.h>

#define BATCH 65536
#define XPER  576      // 24*24 floats per element
#define NBLK  1024
#define EPB   64       // elements per block
#define GPI   16       // elements per staging iteration
#define ITERS (EPB / GPI)

// ws float layout:
//   [0..255]    Ur (row-major 16x16)
//   [256..511]  Ui
//   [512..515]  sum_z[4]
//   [516..519]  sum_z2[4]
//   [520..523]  coef a[4]
//   [524..527]  coef b[4]

// ---------------------------------------------------------------- K1
// Fold the full 2-layer circuit into one 16x16 complex unitary.
// 16 threads, thread j owns column j of M (state' = M state, M starts = I).
__global__ void build_unitary(const float* __restrict__ params,
                              float* __restrict__ ws) {
    int j = threadIdx.x;
    if (j < 8) ws[512 + j] = 0.0f;   // zero BN accumulators every call
    if (j >= 16) return;

    float Mr[16], Mi[16];
#pragma unroll
    for (int i = 0; i < 16; ++i) { Mr[i] = (i == j) ? 1.0f : 0.0f; Mi[i] = 0.0f; }

#pragma unroll
    for (int l = 0; l < 2; ++l) {
        // ---- 4 single-qubit Rot gates (commute across distinct wires)
#pragma unroll
        for (int w = 0; w < 4; ++w) {
            float phi   = params[(l * 4 + w) * 3 + 0];
            float theta = params[(l * 4 + w) * 3 + 1];
            float omega = params[(l * 4 + w) * 3 + 2];
            float c = cosf(0.5f * theta), s = sinf(0.5f * theta);
            float apo = 0.5f * (phi + omega), amo = 0.5f * (phi - omega);
            float epr = cosf(apo), epi = -sinf(apo);   // ep = e^{-i(phi+omega)/2}
            float emr = cosf(amo), emi =  sinf(amo);   // em = e^{+i(phi-omega)/2}
            float m00r =  epr * c, m00i =  epi * c;    // ep*c
            float m01r = -emr * s, m01i = -emi * s;    // -em*s
            float m10r =  emr * s, m10i = -emi * s;    // conj(em)*s
            float m11r =  epr * c, m11i = -epi * c;    // conj(ep)*c
            const int mask = 1 << (3 - w);
#pragma unroll
            for (int i = 0; i < 16; ++i) {
                if (i & mask) continue;
                int i1 = i | mask;
                float r0 = Mr[i],  q0 = Mi[i];
                float r1 = Mr[i1], q1 = Mi[i1];
                Mr[i]  = m00r * r0 - m00i * q0 + m01r * r1 - m01i * q1;
                Mi[i]  = m00r * q0 + m00i * r0 + m01r * q1 + m01i * r1;
                Mr[i1] = m10r * r0 - m10i * q0 + m11r * r1 - m11i * q1;
                Mi[i1] = m10r * q0 + m10i * r0 + m11r * q1 + m11i * r1;
            }
        }
        // ---- CNOT ring: r = l%3+1; perms applied sequentially (XOR involutions)
        const int r = (l % 3) + 1;
#pragma unroll
        for (int w = 0; w < 4; ++w) {
            int tq = (w + r) & 3;
            int cb = 3 - w, tb = 3 - tq;
#pragma unroll
            for (int i = 0; i < 16; ++i) {
                int pi = i ^ (((i >> cb) & 1) << tb);
                if (pi > i) {
                    float tr = Mr[i]; Mr[i] = Mr[pi]; Mr[pi] = tr;
                    float ti = Mi[i]; Mi[i] = Mi[pi]; Mi[pi] = ti;
                }
            }
        }
    }
#pragma unroll
    for (int i = 0; i < 16; ++i) {
        ws[i * 16 + j]       = Mr[i];
        ws[256 + i * 16 + j] = Mi[i];
    }
}

// ---------------------------------------------------------------- K2
// Pool + unitary + probs + WHT z-outputs + BN partial sums.
__global__ __launch_bounds__(256) void circuit_kernel(
        const float* __restrict__ x, const float* __restrict__ wsu,
        float* __restrict__ out, float* __restrict__ accums) {
    __shared__ float sx[GPI * XPER];   // 36 KB staging
    __shared__ float spart[8];

    const int t = threadIdx.x;
    const int e = t >> 4;      // element within group of 16
    const int p = t & 15;      // pool index == state index owned by this lane

    if (t < 8) spart[t] = 0.0f;

    // U row p (broadcast loads, L2-resident)
    float ur[16], ui[16];
#pragma unroll
    for (int j = 0; j < 16; ++j) {
        ur[j] = wsu[p * 16 + j];
        ui[j] = wsu[256 + p * 16 + j];
    }

    // writer lane -> output channel (z_w lives at group-lane 1<<(3-w))
    int c = -1;
    if      (p == 8) c = 0;
    else if (p == 4) c = 1;
    else if (p == 2) c = 2;
    else if (p == 1) c = 3;

    float accz = 0.0f, accz2 = 0.0f;
    const int base = blockIdx.x * EPB;

    for (int it = 0; it < ITERS; ++it) {
        const int ebase = base + it * GPI;
        // stage 16*576 contiguous floats as float4 (coalesced)
        const float4* src = (const float4*)(x + (size_t)ebase * XPER);
        float4* dst = (float4*)sx;
#pragma unroll
        for (int k = 0; k < 9; ++k) dst[k * 256 + t] = src[k * 256 + t];
        __syncthreads();

        // 6x6 average pool, thread p owns pooled[r0/6][c0/6]
        const int r0 = (p >> 2) * 6, c0 = (p & 3) * 6;
        const float* bs = sx + e * XPER + r0 * 24 + c0;
        float sum = 0.0f;
#pragma unroll
        for (int i = 0; i < 6; ++i)
#pragma unroll
            for (int jj = 0; jj < 6; ++jj) sum += bs[i * 24 + jj];
        float v = sum * (1.0f / 36.0f);

        // norm^2 over the 16-lane group
        float n2 = v * v;
        n2 += __shfl_xor(n2, 1);
        n2 += __shfl_xor(n2, 2);
        n2 += __shfl_xor(n2, 4);
        n2 += __shfl_xor(n2, 8);

        // state_p = sum_j U[p][j] * v_j   (input state is real)
        float sr = 0.0f, si = 0.0f;
#pragma unroll
        for (int j = 0; j < 16; ++j) {
            float vj = __shfl(v, j, 16);
            sr = fmaf(ur[j], vj, sr);
            si = fmaf(ui[j], vj, si);
        }
        float prob = (sr * sr + si * si) / n2;

        // 16-pt Walsh-Hadamard: lane m holds sum_p (-1)^{popc(m&p)} prob_p
        float a = prob, o;
        o = __shfl_xor(a, 1); a = (t & 1) ? (o - a) : (a + o);
        o = __shfl_xor(a, 2); a = (t & 2) ? (o - a) : (a + o);
        o = __shfl_xor(a, 4); a = (t & 4) ? (o - a) : (a + o);
        o = __shfl_xor(a, 8); a = (t & 8) ? (o - a) : (a + o);

        if (c >= 0) {
            out[(size_t)(ebase + e) * 4 + c] = a;   // raw z, normalized by K4
            accz  += a;
            accz2 += a * a;
        }
        __syncthreads();   // protect sx before next staging
    }

    if (c >= 0) {
        atomicAdd(&spart[c], accz);
        atomicAdd(&spart[4 + c], accz2);
    }
    __syncthreads();
    if (t < 8) atomicAdd(&accums[t], spart[t]);
}

// ---------------------------------------------------------------- K3
__global__ void finalize_stats(const float* __restrict__ accums,
                               const float* __restrict__ gamma,
                               const float* __restrict__ beta,
                               float* __restrict__ coefs) {
    int t = threadIdx.x;
    if (t < 4) {
        float mu  = accums[t] * (1.0f / BATCH);
        float var = accums[4 + t] * (1.0f / BATCH) - mu * mu;
        float a = gamma[t] * rsqrtf(var + 1e-5f);
        coefs[t]     = a;
        coefs[4 + t] = beta[t] - mu * a;
    }
}

// ---------------------------------------------------------------- K4
__global__ __launch_bounds__(256) void bn_apply(float* __restrict__ out,
                                                const float* __restrict__ coefs) {
    int i = blockIdx.x * 256 + threadIdx.x;   // one float4 (one element) each
    float4 z = ((float4*)out)[i];
    float a0 = coefs[0], a1 = coefs[1], a2 = coefs[2], a3 = coefs[3];
    float b0 = coefs[4], b1 = coefs[5], b2 = coefs[6], b3 = coefs[7];
    z.x = fmaf(z.x, a0, b0);
    z.y = fmaf(z.y, a1, b1);
    z.z = fmaf(z.z, a2, b2);
    z.w = fmaf(z.w, a3, b3);
    ((float4*)out)[i] = z;
}

extern "C" void kernel_launch(void* const* d_in, const int* in_sizes, int n_in,
                              void* d_out, int out_size, void* d_ws, size_t ws_size,
                              hipStream_t stream) {
    const float* x      = (const float*)d_in[0];
    const float* params = (const float*)d_in[1];
    const float* gamma  = (const float*)d_in[2];
    const float* beta   = (const float*)d_in[3];
    float* out = (float*)d_out;
    float* ws  = (float*)d_ws;

    hipLaunchKernelGGL(build_unitary, dim3(1), dim3(64), 0, stream, params, ws);
    hipLaunchKernelGGL(circuit_kernel, dim3(NBLK), dim3(256), 0, stream,
                       x, ws, out, ws + 512);
    hipLaunchKernelGGL(finalize_stats, dim3(1), dim3(64), 0, stream,
                       ws + 512, gamma, beta, ws + 520);
    hipLaunchKernelGGL(bn_apply, dim3(BATCH / 256), dim3(256), 0, stream,
                       out, ws + 520);
}

// Round 2
// 44.972 us; speedup vs baseline: 1.0222x; 1.0222x over previous
//
#include <hip/hip_runtime.h>
#include <math.h>

#define BATCH 65536
#define XPER  576      // 24*24 floats per element
#define NBLK  1024
#define EPB   64       // elements per block
#define GPI   16       // elements per staging iteration
#define ITERS (EPB / GPI)

// ws float layout: [0..3] sum_z, [4..7] sum_z2   (zeroed by memset node)

// ---------------------------------------------------------------- K1
// Pool + folded 2-layer unitary + probs + WHT z-outputs + BN partial sums.
// Each block redundantly builds the 16x16 complex unitary U at start:
//   lanes 0..7  : trig for one gate each -> sg
//   lanes 0..15 : butterfly-fold, lane j owns column j -> sU
//   all threads : load U row p into registers (once)
__global__ __launch_bounds__(256) void circuit_kernel(
        const float* __restrict__ x, const float* __restrict__ params,
        float* __restrict__ out, float* __restrict__ accums) {
    __shared__ float sx[GPI * XPER];   // 36 KB staging
    __shared__ float sU[512];          // Ur row-major, then Ui
    __shared__ float sg[48];           // 8 gates x {c,s,epr,epi,emr,emi}
    __shared__ float spart[8];

    const int t = threadIdx.x;
    const int e = t >> 4;      // element within group of 16
    const int p = t & 15;      // pool index == state row owned by this lane

    if (t < 8) {
        spart[t] = 0.0f;
        // gate t = (layer l = t>>2, wire w = t&3)
        float phi   = params[t * 3 + 0];
        float theta = params[t * 3 + 1];
        float omega = params[t * 3 + 2];
        float apo = 0.5f * (phi + omega), amo = 0.5f * (phi - omega);
        sg[t * 6 + 0] = cosf(0.5f * theta);
        sg[t * 6 + 1] = sinf(0.5f * theta);
        sg[t * 6 + 2] = cosf(apo);           // epr   (ep = e^{-i(phi+omega)/2})
        sg[t * 6 + 3] = -sinf(apo);          // epi
        sg[t * 6 + 4] = cosf(amo);           // emr   (em = e^{+i(phi-omega)/2})
        sg[t * 6 + 5] = sinf(amo);           // emi
    }
    __syncthreads();

    if (t < 16) {
        const int j = t;       // this lane owns column j of M (state' = M state)
        float Mr[16], Mi[16];
#pragma unroll
        for (int i = 0; i < 16; ++i) { Mr[i] = (i == j) ? 1.0f : 0.0f; Mi[i] = 0.0f; }

#pragma unroll
        for (int l = 0; l < 2; ++l) {
#pragma unroll
            for (int w = 0; w < 4; ++w) {
                const int g = l * 4 + w;
                float c   = sg[g * 6 + 0], s   = sg[g * 6 + 1];
                float epr = sg[g * 6 + 2], epi = sg[g * 6 + 3];
                float emr = sg[g * 6 + 4], emi = sg[g * 6 + 5];
                float m00r =  epr * c, m00i =  epi * c;    // ep*c
                float m01r = -emr * s, m01i = -emi * s;    // -em*s
                float m10r =  emr * s, m10i = -emi * s;    // conj(em)*s
                float m11r =  epr * c, m11i = -epi * c;    // conj(ep)*c
                const int mask = 1 << (3 - w);
#pragma unroll
                for (int i = 0; i < 16; ++i) {
                    if (i & mask) continue;
                    int i1 = i | mask;
                    float r0 = Mr[i],  q0 = Mi[i];
                    float r1 = Mr[i1], q1 = Mi[i1];
                    Mr[i]  = m00r * r0 - m00i * q0 + m01r * r1 - m01i * q1;
                    Mi[i]  = m00r * q0 + m00i * r0 + m01r * q1 + m01i * r1;
                    Mr[i1] = m10r * r0 - m10i * q0 + m11r * r1 - m11i * q1;
                    Mi[i1] = m10r * q0 + m10i * r0 + m11r * q1 + m11i * r1;
                }
            }
            // CNOT ring: r = l%3+1; XOR permutations applied sequentially
            const int r = (l % 3) + 1;
#pragma unroll
            for (int w = 0; w < 4; ++w) {
                int tq = (w + r) & 3;
                int cb = 3 - w, tb = 3 - tq;
#pragma unroll
                for (int i = 0; i < 16; ++i) {
                    int pi = i ^ (((i >> cb) & 1) << tb);
                    if (pi > i) {
                        float tr = Mr[i]; Mr[i] = Mr[pi]; Mr[pi] = tr;
                        float ti = Mi[i]; Mi[i] = Mi[pi]; Mi[pi] = ti;
                    }
                }
            }
        }
#pragma unroll
        for (int i = 0; i < 16; ++i) {
            sU[i * 16 + j]       = Mr[i];
            sU[256 + i * 16 + j] = Mi[i];
        }
    }
    __syncthreads();

    // U row p -> registers (float4 LDS reads, once per kernel)
    float ur[16], ui[16];
    {
        const float4* u4 = (const float4*)(sU + p * 16);
        const float4* v4 = (const float4*)(sU + 256 + p * 16);
#pragma unroll
        for (int q = 0; q < 4; ++q) {
            float4 a = u4[q], b = v4[q];
            ur[4 * q + 0] = a.x; ur[4 * q + 1] = a.y; ur[4 * q + 2] = a.z; ur[4 * q + 3] = a.w;
            ui[4 * q + 0] = b.x; ui[4 * q + 1] = b.y; ui[4 * q + 2] = b.z; ui[4 * q + 3] = b.w;
        }
    }

    // writer lane -> output channel (z_w lives at group-lane 1<<(3-w))
    int c = -1;
    if      (p == 8) c = 0;
    else if (p == 4) c = 1;
    else if (p == 2) c = 2;
    else if (p == 1) c = 3;

    float accz = 0.0f, accz2 = 0.0f;
    const int base = blockIdx.x * EPB;

    for (int it = 0; it < ITERS; ++it) {
        const int ebase = base + it * GPI;
        // stage 16*576 contiguous floats as float4 (coalesced)
        const float4* src = (const float4*)(x + (size_t)ebase * XPER);
        float4* dst = (float4*)sx;
#pragma unroll
        for (int k = 0; k < 9; ++k) dst[k * 256 + t] = src[k * 256 + t];
        __syncthreads();

        // 6x6 average pool, thread p owns pooled[r0/6][c0/6]
        const int r0 = (p >> 2) * 6, c0 = (p & 3) * 6;
        const float* bs = sx + e * XPER + r0 * 24 + c0;
        float sum = 0.0f;
#pragma unroll
        for (int i = 0; i < 6; ++i)
#pragma unroll
            for (int jj = 0; jj < 6; ++jj) sum += bs[i * 24 + jj];
        float v = sum * (1.0f / 36.0f);

        // norm^2 over the 16-lane group
        float n2 = v * v;
        n2 += __shfl_xor(n2, 1);
        n2 += __shfl_xor(n2, 2);
        n2 += __shfl_xor(n2, 4);
        n2 += __shfl_xor(n2, 8);

        // state_p = sum_j U[p][j] * v_j   (input state is real)
        float sr = 0.0f, si = 0.0f;
#pragma unroll
        for (int j = 0; j < 16; ++j) {
            float vj = __shfl(v, j, 16);
            sr = fmaf(ur[j], vj, sr);
            si = fmaf(ui[j], vj, si);
        }
        float prob = (sr * sr + si * si) / n2;

        // 16-pt Walsh-Hadamard: lane m holds sum_p (-1)^{popc(m&p)} prob_p
        float a = prob, o;
        o = __shfl_xor(a, 1); a = (t & 1) ? (o - a) : (a + o);
        o = __shfl_xor(a, 2); a = (t & 2) ? (o - a) : (a + o);
        o = __shfl_xor(a, 4); a = (t & 4) ? (o - a) : (a + o);
        o = __shfl_xor(a, 8); a = (t & 8) ? (o - a) : (a + o);

        if (c >= 0) {
            out[(size_t)(ebase + e) * 4 + c] = a;   // raw z, normalized by K2
            accz  += a;
            accz2 += a * a;
        }
        __syncthreads();   // protect sx before next staging
    }

    if (c >= 0) {
        atomicAdd(&spart[c], accz);
        atomicAdd(&spart[4 + c], accz2);
    }
    __syncthreads();
    if (t < 8) atomicAdd(&accums[t], spart[t]);
}

// ---------------------------------------------------------------- K2
// Finalize BN stats (per-block, cheap) + apply affine to out in place.
__global__ __launch_bounds__(256) void bn_apply(float* __restrict__ out,
                                                const float* __restrict__ accums,
                                                const float* __restrict__ gamma,
                                                const float* __restrict__ beta) {
    __shared__ float sc[8];
    const int t = threadIdx.x;
    if (t < 4) {
        float mu  = accums[t] * (1.0f / BATCH);
        float var = accums[4 + t] * (1.0f / BATCH) - mu * mu;
        float a = gamma[t] * rsqrtf(var + 1e-5f);
        sc[t]     = a;
        sc[4 + t] = beta[t] - mu * a;
    }
    __syncthreads();
    int i = blockIdx.x * 256 + t;   // one float4 (one element) each
    float4 z = ((float4*)out)[i];
    z.x = fmaf(z.x, sc[0], sc[4]);
    z.y = fmaf(z.y, sc[1], sc[5]);
    z.z = fmaf(z.z, sc[2], sc[6]);
    z.w = fmaf(z.w, sc[3], sc[7]);
    ((float4*)out)[i] = z;
}

extern "C" void kernel_launch(void* const* d_in, const int* in_sizes, int n_in,
                              void* d_out, int out_size, void* d_ws, size_t ws_size,
                              hipStream_t stream) {
    const float* x      = (const float*)d_in[0];
    const float* params = (const float*)d_in[1];
    const float* gamma  = (const float*)d_in[2];
    const float* beta   = (const float*)d_in[3];
    float* out = (float*)d_out;
    float* ws  = (float*)d_ws;

    hipMemsetAsync(ws, 0, 8 * sizeof(float), stream);   // zero BN accumulators
    hipLaunchKernelGGL(circuit_kernel, dim3(NBLK), dim3(256), 0, stream,
                       x, params, out, ws);
    hipLaunchKernelGGL(bn_apply, dim3(BATCH / 256), dim3(256), 0, stream,
                       out, ws, gamma, beta);
}